// Round 11
// baseline (130.702 us; speedup 1.0000x reference)
//
#include <hip/hip_runtime.h>
#include <hip/hip_bf16.h>

typedef __bf16 bf16x8 __attribute__((ext_vector_type(8)));
typedef float  f32x4  __attribute__((ext_vector_type(4)));

// ---------------------------------------------------------------------------
// Stage 1: qkv = kern_tok @ qkv_w + qkv_b ; split into q(scaled),k,v
// ---------------------------------------------------------------------------
__global__ __launch_bounds__(192) void qkv_kernel(
    const float* __restrict__ conv_w, const float* __restrict__ qkv_w,
    const float* __restrict__ qkv_b,
    float* __restrict__ qv, float* __restrict__ kvv, float* __restrict__ vv)
{
    __shared__ float tok[64];
    const int bid = blockIdx.x;          // co*36 + s
    const int co = bid / 36, s = bid - co * 36;
    const int w = s / 9, p = s - w * 9;
    const int t = threadIdx.x;           // 192
    if (t < 64) tok[t] = conv_w[(((w * 64 + co) * 64 + t) * 9) + p];
    __syncthreads();
    float acc = qkv_b[t];
#pragma unroll 8
    for (int ci = 0; ci < 64; ++ci) acc += tok[ci] * qkv_w[ci * 192 + t];
    const int trip = t >> 6, rem = t & 63, h = rem >> 3, d = rem & 7;
    if (trip == 0) acc *= 0.35355339059327373f;   // hd^-0.5, hd=8
    float* dst = (trip == 0) ? qv : ((trip == 1) ? kvv : vv);
    dst[((co * 8 + h) * 36 + s) * 8 + d] = acc;
}

// ---------------------------------------------------------------------------
// Stage 2: attention per (co, head): softmax(q k^T) v  -> ao[co][s][h*8+d]
// ---------------------------------------------------------------------------
__global__ __launch_bounds__(64) void attn_kernel(
    const float* __restrict__ qv, const float* __restrict__ kvv,
    const float* __restrict__ vv, float* __restrict__ ao)
{
    __shared__ float kl[288], vl[288];
    const int bid = blockIdx.x;          // co*8 + h
    const int t = threadIdx.x;           // 64
    const float* kb = kvv + bid * 288;
    const float* vb = vv + bid * 288;
    for (int i = t; i < 288; i += 64) { kl[i] = kb[i]; vl[i] = vb[i]; }
    __syncthreads();
    if (t < 36) {
        float q[8];
        const float* qb = qv + bid * 288 + t * 8;
#pragma unroll
        for (int d = 0; d < 8; ++d) q[d] = qb[d];
        float sc[36];
        float mx = -1e30f;
#pragma unroll
        for (int u = 0; u < 36; ++u) {
            float a = 0.f;
#pragma unroll
            for (int d = 0; d < 8; ++d) a += q[d] * kl[u * 8 + d];
            sc[u] = a;
            mx = fmaxf(mx, a);
        }
        float sum = 0.f;
        float o[8] = {0.f,0.f,0.f,0.f,0.f,0.f,0.f,0.f};
#pragma unroll
        for (int u = 0; u < 36; ++u) {
            float e = expf(sc[u] - mx);
            sum += e;
#pragma unroll
            for (int d = 0; d < 8; ++d) o[d] += e * vl[u * 8 + d];
        }
        const float inv = 1.0f / sum;
        const int co = bid >> 3, h = bid & 7;
        float* dst = ao + (co * 36 + t) * 64 + h * 8;
#pragma unroll
        for (int d = 0; d < 8; ++d) dst[d] = o[d] * inv;
    }
}

// ---------------------------------------------------------------------------
// Stage 3: proj + SE + write bf16 kernels.
// kout layout: [((h*4 + w)*9 + p)][co][ci32]  (4 KB chunks = one
// (tap, ci-half); conv stages exactly one chunk per pipeline stage).
// ---------------------------------------------------------------------------
__global__ __launch_bounds__(64) void proj_se_kernel(
    const float* __restrict__ ao, const float* __restrict__ proj_w,
    const float* __restrict__ proj_b,
    const float* __restrict__ se_w1, const float* __restrict__ se_b1,
    const float* __restrict__ se_w2, const float* __restrict__ se_b2,
    ushort* __restrict__ kout)
{
    __shared__ float al[9][64];
    __shared__ float pool[64];
    __shared__ float hb[4];
    const int bid = blockIdx.x;          // w*64 + co
    const int w = bid >> 6, co = bid & 63;
    const int t = threadIdx.x;           // 64 (= ci)
    for (int i = t; i < 576; i += 64) {
        int p = i >> 6, j = i & 63;
        al[p][j] = ao[(co * 36 + w * 9 + p) * 64 + j];
    }
    __syncthreads();
    float kv[9];
#pragma unroll
    for (int p = 0; p < 9; ++p) {
        float a = proj_b[t];
#pragma unroll 8
        for (int j = 0; j < 64; ++j) a += al[p][j] * proj_w[j * 64 + t];
        kv[p] = a;
    }
    float pl = 0.f;
#pragma unroll
    for (int p = 0; p < 9; ++p) pl += kv[p];
    pool[t] = pl * (1.0f / 9.0f);
    __syncthreads();
    if (t < 4) {
        float hh = se_b1[w * 4 + t];
#pragma unroll 8
        for (int c = 0; c < 64; ++c) hh += pool[c] * se_w1[(w * 4 + t) * 64 + c];
        hb[t] = fmaxf(hh, 0.0f);
    }
    __syncthreads();
    float z = se_b2[w * 64 + t];
#pragma unroll
    for (int d = 0; d < 4; ++d) z += hb[d] * se_w2[(w * 64 + t) * 4 + d];
    const float sg = 1.0f / (1.0f + expf(-z));
    const int hhalf = t >> 5, ci32 = t & 31;
#pragma unroll
    for (int p = 0; p < 9; ++p) {
        __hip_bfloat16 hv = __float2bfloat16(kv[p] * sg);
        kout[(((hhalf * 4 + w) * 9) + p) * 2048 + co * 32 + ci32] = *(const ushort*)&hv;
    }
}

// ---------------------------------------------------------------------------
// Stage 4: dynamic per-window 3x3 conv, implicit GEMM, bf16 MFMA.
//
// Round-11 = R10's structure with the SPILL removed. R10's regression was
// scratch traffic (WRITE 1.81x ideal with a byte-identical store path to
// R6's exactly-ideal; FETCH +54 MB): __launch_bounds__(256,4) caps the
// unified VGPR+AGPR budget at 128/wave, and acc(64 AGPR) + v[6] restage
// batches(24) + Kf/addressing(~40) hit the cap -> allocator spilled.
// Fixes (everything else byte-identical to R10, which PASSED):
//  - restage batches v[4] (4/4/3): peak during mid-loop restage ~110/128,
//    ~18 regs headroom instead of 0.
//  - per-mf epilogue s_barrier dropped (ep region is wave-private; R6
//    verified correct without it).
// Kill-switch: WRITE_SIZE must return to ~131072 KB. If it stays >=180 MB
// the (256,4) path is dead and R6 is the keeper.
// ---------------------------------------------------------------------------
__global__ __launch_bounds__(256, 4) void conv_kernel(
    const float* __restrict__ x, const ushort* __restrict__ kern,
    float* __restrict__ out)
{
    __shared__ alignas(16) ushort in_lds[18 * 18 * 32];   // 20736 B
    __shared__ alignas(16) ushort kn_lds[4 * 2048];       // 16384 B (4 x 4KB)

    const int tid = threadIdx.x;

    // ---- XCD-chunked bijective remap: XCD k processes nb in [k*256,(k+1)*256)
    const int bid = blockIdx.x;                 // 0..2047, xcd = bid & 7
    const int nb  = ((bid & 7) << 8) + (bid >> 3);
    const int bz  = nb >> 6;                    // (w*8+b), 4 per XCD
    const int rem = nb & 63;
    const int i0  = (rem >> 3) << 4;
    const int j0  = (rem & 7) << 4;
    const int w = bz >> 3, b = bz & 7;
    const int gi = w >> 1, gj = w & 1;

    const int wv   = tid >> 6;
    const int lane = tid & 63;
    const int l15  = lane & 15;
    const int hi4  = lane >> 4;        // 0..3

    // ---- async kern stage: stage s -> (hh = s<9?0:1, p = s<9?s:s-9), one
    // 4 KB chunk at kern + (((hh*4+w)*9)+p)*4096. Linear LDS dest; read-side
    // swizzle realized by pre-swizzling the GLOBAL source (both-sides rule).
    const char* kern_b = (const char*)kern;
    const int ksrc = (lane << 4) ^ (((lane >> 3) & 3) << 4);
    auto stage_kern = [&](int s, int buf) {
        const int hh = (s < 9) ? 0 : 1;
        const int p  = (s < 9) ? s : s - 9;
        const char* gs = kern_b + ((size_t)((((hh * 4 + w) * 9)) + p) << 12);
        __builtin_amdgcn_global_load_lds(
            (const __attribute__((address_space(1))) unsigned int*)(gs + (wv << 10) + ksrc),
            (__attribute__((address_space(3))) unsigned int*)
                ((char*)kn_lds + (buf << 12) + (wv << 10)),
            16, 0, 0);
    };

    // ---- input staging, one ci-half: 18x18 px * 64 B. 8 thr/px (4 ch);
    // 11 clamped unconditional loads in 3 batches (4/4/3) -- v[4] keeps
    // peak register pressure ~110/128 while acc is live (the R10 spiller
    // used v[6] and hit the cap exactly).
    // LDS position: (pp<<6) + ((cc*2) ^ (((pp>>1)&3)<<4))  [R4-verified]
    auto stage_input = [&](int h) {
        const int cc = (tid & 7) << 2;     // channel-in-half 0..28
        const int p0 = tid >> 3;           // 0..31
#pragma unroll
        for (int batch = 0; batch < 3; ++batch) {
            const int kbeg = batch * 4;
            const int kend = (batch == 2) ? 11 : (kbeg + 4);
            float4 v[4];
            unsigned okm = 0;
#pragma unroll
            for (int k = kbeg; k < kend; ++k) {
                const int pp = p0 + (k << 5);              // <= 351
                const int ppc = pp < 323 ? pp : 323;
                const int r = ppc / 18, q = ppc - r * 18;
                const int iy = i0 - 1 + r, jx = j0 - 1 + q;
                const bool ok = (pp < 324) & (iy >= 0) & (iy < 128) & (jx >= 0) & (jx < 128);
                const int iyc = iy < 0 ? 0 : (iy > 127 ? 127 : iy);
                const int jxc = jx < 0 ? 0 : (jx > 127 ? 127 : jx);
                const size_t xi = (((size_t)b << 16) +
                                   (size_t)(gi * 128 + iyc) * 256 + (size_t)(gj * 128 + jxc)) * 64 +
                                  h * 32 + cc;
                v[k - kbeg] = *(const float4*)(x + xi);
                okm |= (unsigned)ok << (k - kbeg);
            }
#pragma unroll
            for (int k = kbeg; k < kend; ++k) {
                const int pp = p0 + (k << 5);
                if (pp < 324) {
                    float4 z = (okm >> (k - kbeg)) & 1 ? v[k - kbeg]
                                                       : make_float4(0.f, 0.f, 0.f, 0.f);
                    union { ushort4 u; ushort h4[4]; } tmp;
                    __hip_bfloat16 b0 = __float2bfloat16(z.x); tmp.h4[0] = *(const ushort*)&b0;
                    __hip_bfloat16 b1 = __float2bfloat16(z.y); tmp.h4[1] = *(const ushort*)&b1;
                    __hip_bfloat16 b2 = __float2bfloat16(z.z); tmp.h4[2] = *(const ushort*)&b2;
                    __hip_bfloat16 b3 = __float2bfloat16(z.w); tmp.h4[3] = *(const ushort*)&b3;
                    *(ushort4*)((char*)in_lds +
                        ((pp << 6) + ((cc << 1) ^ (((pp >> 1) & 3) << 4)))) = tmp.u;
                }
            }
        }
    };

    f32x4 acc[4][4];
#pragma unroll
    for (int mf = 0; mf < 4; ++mf)
#pragma unroll
        for (int nf = 0; nf < 4; ++nf)
            acc[mf][nf] = (f32x4){0.f, 0.f, 0.f, 0.f};

    // ---- prologue: issue kern sets 0,1,2 (fly under the staging burst),
    // stage input half 0, ONE full drain.
    stage_kern(0, 0);
    stage_kern(1, 1);
    stage_kern(2, 2);
    stage_input(0);
    __syncthreads();     // drains input ds_writes + kern sets 0,1,2

#pragma unroll
    for (int s = 0; s < 18; ++s) {
        if (s == 9) {
            // all waves done with half-0 Af reads; restage with half 1.
            // __syncthreads fully drains vmcnt (sets 9,10,11 land early --
            // harmless); after restage the counted scheme resumes exactly.
            __syncthreads();
            stage_input(1);
            __syncthreads();
        }

        // counted wait: set s retired (outstanding <= {s, s+1, s+2}).
        if (s < 16)       asm volatile("s_waitcnt vmcnt(2)" ::: "memory");
        else if (s == 16) asm volatile("s_waitcnt vmcnt(1)" ::: "memory");
        else              asm volatile("s_waitcnt vmcnt(0)" ::: "memory");
        __builtin_amdgcn_sched_barrier(0);
        __builtin_amdgcn_s_barrier();      // all waves' set-s loads in LDS
        __builtin_amdgcn_sched_barrier(0);

        // issue set s+3 into buf (s+3)&3 = (s-1)&3: all waves passed the
        // barrier => all finished compute(s-1) = last readers of that buf.
        if (s <= 14) stage_kern(s + 3, (s + 3) & 3);

        const int buf = s & 3;
        const int p  = (s < 9) ? s : s - 9;
        const int kh = p / 3, kw = p - kh * 3;

        // kern fragments: co = nf*16+l15, ci-chunk hi4 within this half
        bf16x8 Kf[4];
#pragma unroll
        for (int nf = 0; nf < 4; ++nf) {
            const int co = nf * 16 + l15;
            Kf[nf] = *(const bf16x8*)((const char*)kn_lds +
                      ((buf << 12) + (co << 6) +
                       ((hi4 << 4) ^ (((co >> 1) & 3) << 4))));
        }

        const int q = l15 + kw;
#pragma unroll
        for (int mf = 0; mf < 4; ++mf) {
            const int r = wv * 4 + mf + kh;
            const int px = r * 18 + q;
            bf16x8 Af = *(const bf16x8*)((const char*)in_lds +
                          ((px << 6) + ((hi4 << 4) ^ (((px >> 1) & 3) << 4))));
#pragma unroll
            for (int nf = 0; nf < 4; ++nf)
                acc[mf][nf] = __builtin_amdgcn_mfma_f32_16x16x32_bf16(
                    Kf[nf], Af, acc[mf][nf], 0, 0, 0);
        }
    }

    __syncthreads();     // all waves done reading in_lds before overwrite

    // ---- LDS-transpose epilogue (wave-private 4 KB region, 16 KB total
    // <= 20736 B in_lds). Plain cached stores, 1 KB contiguous per
    // wave-instruction (R6-verified: WRITE_SIZE exactly ideal).
    char* ep = (char*)in_lds + (wv << 12);
#pragma unroll
    for (int mf = 0; mf < 4; ++mf) {
        const int iloc = wv * 4 + mf;
        const size_t rowoff = ((size_t)b << 16) +
                              (size_t)(gi * 128 + i0 + iloc) * 256 + (size_t)(gj * 128 + j0);
        // scatter: lane(l15,hi4) holds co = nf*16+hi4*4+reg at pixel l15
#pragma unroll
        for (int nf = 0; nf < 4; ++nf) {
            const int off = (nf * 64 + hi4 * 16) ^ ((l15 & 7) << 4);
            *(f32x4*)(ep + l15 * 256 + off) = acc[mf][nf];
        }
        // gather: lane(l15,hi4) reads co-chunk l15 of pixel t*4+hi4
#pragma unroll
        for (int t = 0; t < 4; ++t) {
            const int px = t * 4 + hi4;
            f32x4 vv4 = *(const f32x4*)(ep + px * 256 + ((l15 << 4) ^ ((px & 7) << 4)));
            *(f32x4*)(out + (rowoff + px) * 64 + l15 * 4) = vv4;
        }
    }
}

// ---------------------------------------------------------------------------
extern "C" void kernel_launch(void* const* d_in, const int* in_sizes, int n_in,
                              void* d_out, int out_size, void* d_ws, size_t ws_size,
                              hipStream_t stream)
{
    const float* x      = (const float*)d_in[0];
    const float* conv_w = (const float*)d_in[1];
    const float* qkv_w  = (const float*)d_in[2];
    const float* qkv_b  = (const float*)d_in[3];
    const float* proj_w = (const float*)d_in[4];
    const float* proj_b = (const float*)d_in[5];
    const float* se_w1  = (const float*)d_in[6];
    const float* se_b1  = (const float*)d_in[7];
    const float* se_w2  = (const float*)d_in[8];
    const float* se_b2  = (const float*)d_in[9];
    float* out = (float*)d_out;

    float* qv = (float*)d_ws;            // 147456 f
    float* kv = qv + 147456;             // 147456 f
    float* vv = kv + 147456;             // 147456 f
    float* ao = vv + 147456;             // 147456 f
    ushort* kb = (ushort*)(ao + 147456); // 147456 u16  (total ~2.6 MB)

    hipLaunchKernelGGL(qkv_kernel, dim3(2304), dim3(192), 0, stream,
                       conv_w, qkv_w, qkv_b, qv, kv, vv);
    hipLaunchKernelGGL(attn_kernel, dim3(512), dim3(64), 0, stream, qv, kv, vv, ao);
    hipLaunchKernelGGL(proj_se_kernel, dim3(256), dim3(64), 0, stream,
                       ao, proj_w, proj_b, se_w1, se_b1, se_w2, se_b2, kb);
    hipLaunchKernelGGL(conv_kernel, dim3(2048), dim3(256), 0, stream, x, kb, out);
}

// Round 12
// 113.909 us; speedup vs baseline: 1.1474x; 1.1474x over previous
//
#include <hip/hip_runtime.h>
#include <hip/hip_bf16.h>

typedef __bf16 bf16x8 __attribute__((ext_vector_type(8)));
typedef float  f32x4  __attribute__((ext_vector_type(4)));

// ---------------------------------------------------------------------------
// Stage 1: qkv = kern_tok @ qkv_w + qkv_b ; split into q(scaled),k,v
// ---------------------------------------------------------------------------
__global__ __launch_bounds__(192) void qkv_kernel(
    const float* __restrict__ conv_w, const float* __restrict__ qkv_w,
    const float* __restrict__ qkv_b,
    float* __restrict__ qv, float* __restrict__ kvv, float* __restrict__ vv)
{
    __shared__ float tok[64];
    const int bid = blockIdx.x;          // co*36 + s
    const int co = bid / 36, s = bid - co * 36;
    const int w = s / 9, p = s - w * 9;
    const int t = threadIdx.x;           // 192
    if (t < 64) tok[t] = conv_w[(((w * 64 + co) * 64 + t) * 9) + p];
    __syncthreads();
    float acc = qkv_b[t];
#pragma unroll 8
    for (int ci = 0; ci < 64; ++ci) acc += tok[ci] * qkv_w[ci * 192 + t];
    const int trip = t >> 6, rem = t & 63, h = rem >> 3, d = rem & 7;
    if (trip == 0) acc *= 0.35355339059327373f;   // hd^-0.5, hd=8
    float* dst = (trip == 0) ? qv : ((trip == 1) ? kvv : vv);
    dst[((co * 8 + h) * 36 + s) * 8 + d] = acc;
}

// ---------------------------------------------------------------------------
// Stage 2: attention per (co, head): softmax(q k^T) v  -> ao[co][s][h*8+d]
// ---------------------------------------------------------------------------
__global__ __launch_bounds__(64) void attn_kernel(
    const float* __restrict__ qv, const float* __restrict__ kvv,
    const float* __restrict__ vv, float* __restrict__ ao)
{
    __shared__ float kl[288], vl[288];
    const int bid = blockIdx.x;          // co*8 + h
    const int t = threadIdx.x;           // 64
    const float* kb = kvv + bid * 288;
    const float* vb = vv + bid * 288;
    for (int i = t; i < 288; i += 64) { kl[i] = kb[i]; vl[i] = vb[i]; }
    __syncthreads();
    if (t < 36) {
        float q[8];
        const float* qb = qv + bid * 288 + t * 8;
#pragma unroll
        for (int d = 0; d < 8; ++d) q[d] = qb[d];
        float sc[36];
        float mx = -1e30f;
#pragma unroll
        for (int u = 0; u < 36; ++u) {
            float a = 0.f;
#pragma unroll
            for (int d = 0; d < 8; ++d) a += q[d] * kl[u * 8 + d];
            sc[u] = a;
            mx = fmaxf(mx, a);
        }
        float sum = 0.f;
        float o[8] = {0.f,0.f,0.f,0.f,0.f,0.f,0.f,0.f};
#pragma unroll
        for (int u = 0; u < 36; ++u) {
            float e = expf(sc[u] - mx);
            sum += e;
#pragma unroll
            for (int d = 0; d < 8; ++d) o[d] += e * vl[u * 8 + d];
        }
        const float inv = 1.0f / sum;
        const int co = bid >> 3, h = bid & 7;
        float* dst = ao + (co * 36 + t) * 64 + h * 8;
#pragma unroll
        for (int d = 0; d < 8; ++d) dst[d] = o[d] * inv;
    }
}

// ---------------------------------------------------------------------------
// Stage 3: proj + SE + write bf16 kernels.
// kout layout: [((h*4 + w)*9 + p)][co][ci32]  (4 KB chunks = one
// (tap, ci-half); conv stages exactly one chunk per pipeline stage).
// ---------------------------------------------------------------------------
__global__ __launch_bounds__(64) void proj_se_kernel(
    const float* __restrict__ ao, const float* __restrict__ proj_w,
    const float* __restrict__ proj_b,
    const float* __restrict__ se_w1, const float* __restrict__ se_b1,
    const float* __restrict__ se_w2, const float* __restrict__ se_b2,
    ushort* __restrict__ kout)
{
    __shared__ float al[9][64];
    __shared__ float pool[64];
    __shared__ float hb[4];
    const int bid = blockIdx.x;          // w*64 + co
    const int w = bid >> 6, co = bid & 63;
    const int t = threadIdx.x;           // 64 (= ci)
    for (int i = t; i < 576; i += 64) {
        int p = i >> 6, j = i & 63;
        al[p][j] = ao[(co * 36 + w * 9 + p) * 64 + j];
    }
    __syncthreads();
    float kv[9];
#pragma unroll
    for (int p = 0; p < 9; ++p) {
        float a = proj_b[t];
#pragma unroll 8
        for (int j = 0; j < 64; ++j) a += al[p][j] * proj_w[j * 64 + t];
        kv[p] = a;
    }
    float pl = 0.f;
#pragma unroll
    for (int p = 0; p < 9; ++p) pl += kv[p];
    pool[t] = pl * (1.0f / 9.0f);
    __syncthreads();
    if (t < 4) {
        float hh = se_b1[w * 4 + t];
#pragma unroll 8
        for (int c = 0; c < 64; ++c) hh += pool[c] * se_w1[(w * 4 + t) * 64 + c];
        hb[t] = fmaxf(hh, 0.0f);
    }
    __syncthreads();
    float z = se_b2[w * 64 + t];
#pragma unroll
    for (int d = 0; d < 4; ++d) z += hb[d] * se_w2[(w * 64 + t) * 4 + d];
    const float sg = 1.0f / (1.0f + expf(-z));
    const int hhalf = t >> 5, ci32 = t & 31;
#pragma unroll
    for (int p = 0; p < 9; ++p) {
        __hip_bfloat16 hv = __float2bfloat16(kv[p] * sg);
        kout[(((hhalf * 4 + w) * 9) + p) * 2048 + co * 32 + ci32] = *(const ushort*)&hv;
    }
}

// ---------------------------------------------------------------------------
// Stage 4: dynamic per-window 3x3 conv, implicit GEMM, bf16 MFMA.
//
// Round-12 = R6 (best, 84us; counted-vmcnt kern triple-buffer, full-channel
// in_lds, (256,3)) + WOVEN INPUT STAGING: prologue stages only ci-half 0
// (11 loads instead of 21); half-1's 11 loads are woven through stages 0-8
// in 3-load register batches (issue@s0/2/4/6, explicit vmcnt(2) + ds_write
// @s2/4/6/8, +12 regs peak -- fits R6's 22-reg headroom at (256,3); the
// (256,4) spill wall of R10/R11 is avoided entirely). Loop is half-major
// (s<9: taps 0-8 of half 0; s>=9: half 1 -- R10/R11-verified mapping, same
// kout layout). lgkmcnt(0) before the s9 barrier publishes half 1.
// vmcnt schedule (exact, derived from the per-wave issue queue where each
// stage_kern = 1 op and input batches = 3/3/3/2 ops):
//   s=1..6: vmcnt(4); s=7,8: vmcnt(3); s>=9: vmcnt(1); batch writes use
//   explicit vmcnt(2) (kern s+1,s+2 stay in flight -- never drained).
// Kill-switch: WRITE_SIZE must stay ~131072 KB; VGPR ~95-110.
// ---------------------------------------------------------------------------
__global__ __launch_bounds__(256, 3) void conv_kernel(
    const float* __restrict__ x, const ushort* __restrict__ kern,
    float* __restrict__ out)
{
    __shared__ alignas(16) ushort in_lds[18 * 18 * 64];   // 41472 B
    __shared__ alignas(16) ushort kn_lds[3 * 2048];       // 12288 B (3 x 4KB)

    const int tid = threadIdx.x;

    // ---- XCD-chunked bijective remap: XCD k processes nb in [k*256,(k+1)*256)
    const int bid = blockIdx.x;                 // 0..2047, xcd = bid & 7
    const int nb  = ((bid & 7) << 8) + (bid >> 3);
    const int bz  = nb >> 6;                    // (w*8+b), 4 per XCD
    const int rem = nb & 63;
    const int i0  = (rem >> 3) << 4;
    const int j0  = (rem & 7) << 4;
    const int w = bz >> 3, b = bz & 7;
    const int gi = w >> 1, gj = w & 1;

    const int wv   = tid >> 6;
    const int lane = tid & 63;
    const int l15  = lane & 15;
    const int hi4  = lane >> 4;        // 0..3

    // ---- async kern stage: stage s -> (hh = s<9?0:1, p = s%9), one 4 KB
    // chunk. Linear LDS dest; read-side swizzle realized by pre-swizzling
    // the GLOBAL source (R6-verified pair).
    const char* kern_b = (const char*)kern;
    const int ksrc = (lane << 4) ^ (((lane >> 3) & 3) << 4);
    auto stage_kern = [&](int s, int buf) {
        const int hh = (s < 9) ? 0 : 1;
        const int p  = (s < 9) ? s : s - 9;
        const char* gs = kern_b + ((size_t)((((hh * 4 + w) * 9)) + p) << 12);
        __builtin_amdgcn_global_load_lds(
            (const __attribute__((address_space(1))) unsigned int*)(gs + (wv << 10) + ksrc),
            (__attribute__((address_space(3))) unsigned int*)
                ((char*)kn_lds + (buf << 12) + (wv << 10)),
            16, 0, 0);
    };

    // ---- input staging geometry: 8 thr/px (4 ch of one half each),
    // p0 strides 32 px, 11 k-iterations cover 324 px.
    // LDS byte pos: (pp<<7) + (((h<<6)+(cc<<1)) ^ ((q&7)<<4))  [R6 swizzle]
    const int cc = (tid & 7) << 2;     // channel-in-half 0..28
    const int p0 = tid >> 3;           // 0..31

    float4 hold[3];
    unsigned okm = 0;

    auto issue_inp1 = [&](int kbeg, int kend) {   // half 1 -> registers
        okm = 0;
#pragma unroll
        for (int k = kbeg; k < kend; ++k) {
            const int pp = p0 + (k << 5);
            const int ppc = pp < 323 ? pp : 323;
            const int r = ppc / 18, q = ppc - r * 18;
            const int iy = i0 - 1 + r, jx = j0 - 1 + q;
            const bool ok = (pp < 324) & (iy >= 0) & (iy < 128) & (jx >= 0) & (jx < 128);
            const int iyc = iy < 0 ? 0 : (iy > 127 ? 127 : iy);
            const int jxc = jx < 0 ? 0 : (jx > 127 ? 127 : jx);
            const size_t xi = (((size_t)b << 16) +
                               (size_t)(gi * 128 + iyc) * 256 + (size_t)(gj * 128 + jxc)) * 64 +
                              32 + cc;
            hold[k - kbeg] = *(const float4*)(x + xi);
            okm |= (unsigned)ok << (k - kbeg);
        }
    };
    auto write_inp1 = [&](int kbeg, int kend) {   // registers -> LDS (half 1)
#pragma unroll
        for (int k = kbeg; k < kend; ++k) {
            const int pp = p0 + (k << 5);
            if (pp < 324) {
                const int r = pp / 18, q = pp - r * 18;
                float4 z = (okm >> (k - kbeg)) & 1 ? hold[k - kbeg]
                                                   : make_float4(0.f, 0.f, 0.f, 0.f);
                union { ushort4 u; ushort h4[4]; } tmp;
                __hip_bfloat16 b0 = __float2bfloat16(z.x); tmp.h4[0] = *(const ushort*)&b0;
                __hip_bfloat16 b1 = __float2bfloat16(z.y); tmp.h4[1] = *(const ushort*)&b1;
                __hip_bfloat16 b2 = __float2bfloat16(z.z); tmp.h4[2] = *(const ushort*)&b2;
                __hip_bfloat16 b3 = __float2bfloat16(z.w); tmp.h4[3] = *(const ushort*)&b3;
                *(ushort4*)((char*)in_lds +
                    ((pp << 7) + (((1 << 6) + (cc << 1)) ^ ((q & 7) << 4)))) = tmp.u;
            }
        }
    };

    f32x4 acc[4][4];
#pragma unroll
    for (int mf = 0; mf < 4; ++mf)
#pragma unroll
        for (int nf = 0; nf < 4; ++nf)
            acc[mf][nf] = (f32x4){0.f, 0.f, 0.f, 0.f};

    // ---- prologue: kern sets 0,1 async; input HALF 0 only (11 loads,
    // issued as one burst before the cvt/write pass); one full drain.
    stage_kern(0, 0);
    stage_kern(1, 1);
    {
        float4 v[11];
        unsigned ok0 = 0;
#pragma unroll
        for (int k = 0; k < 11; ++k) {
            const int pp = p0 + (k << 5);
            const int ppc = pp < 323 ? pp : 323;
            const int r = ppc / 18, q = ppc - r * 18;
            const int iy = i0 - 1 + r, jx = j0 - 1 + q;
            const bool ok = (pp < 324) & (iy >= 0) & (iy < 128) & (jx >= 0) & (jx < 128);
            const int iyc = iy < 0 ? 0 : (iy > 127 ? 127 : iy);
            const int jxc = jx < 0 ? 0 : (jx > 127 ? 127 : jx);
            const size_t xi = (((size_t)b << 16) +
                               (size_t)(gi * 128 + iyc) * 256 + (size_t)(gj * 128 + jxc)) * 64 + cc;
            v[k] = *(const float4*)(x + xi);
            ok0 |= (unsigned)ok << k;
        }
#pragma unroll
        for (int k = 0; k < 11; ++k) {
            const int pp = p0 + (k << 5);
            if (pp < 324) {
                const int r = pp / 18, q = pp - r * 18;
                float4 z = (ok0 >> k) & 1 ? v[k] : make_float4(0.f, 0.f, 0.f, 0.f);
                union { ushort4 u; ushort h4[4]; } tmp;
                __hip_bfloat16 b0 = __float2bfloat16(z.x); tmp.h4[0] = *(const ushort*)&b0;
                __hip_bfloat16 b1 = __float2bfloat16(z.y); tmp.h4[1] = *(const ushort*)&b1;
                __hip_bfloat16 b2 = __float2bfloat16(z.z); tmp.h4[2] = *(const ushort*)&b2;
                __hip_bfloat16 b3 = __float2bfloat16(z.w); tmp.h4[3] = *(const ushort*)&b3;
                *(ushort4*)((char*)in_lds +
                    ((pp << 7) + ((cc << 1) ^ ((q & 7) << 4)))) = tmp.u;
            }
        }
    }
    __syncthreads();     // drains half-0 ds_writes + kern sets 0,1

#pragma unroll
    for (int s = 0; s < 18; ++s) {
        // counted wait: kern set s retired (exact per-stage queue depth)
        if (s >= 1 && s <= 6)      asm volatile("s_waitcnt vmcnt(4)" ::: "memory");
        else if (s == 7 || s == 8) asm volatile("s_waitcnt vmcnt(3)" ::: "memory");
        else if (s >= 9)           asm volatile("s_waitcnt vmcnt(1)" ::: "memory");
        __builtin_amdgcn_sched_barrier(0);
        if (s == 9) {
            // publish my half-1 ds_writes before anyone reads half 1
            asm volatile("s_waitcnt lgkmcnt(0)" ::: "memory");
            __builtin_amdgcn_sched_barrier(0);
        }
        __builtin_amdgcn_s_barrier();      // all waves' set-s loads in LDS
        __builtin_amdgcn_sched_barrier(0);

        // issue kern set s+2 into buf (s+2)%3 (last read at stage s-1)
        if (s < 16) stage_kern(s + 2, (s + 2) % 3);

        // weave half-1 input staging through stages 0-8
        if (s == 0) { issue_inp1(0, 3); }
        else if (s == 2) {
            asm volatile("s_waitcnt vmcnt(2)" ::: "memory");   // batch A in
            __builtin_amdgcn_sched_barrier(0);
            write_inp1(0, 3); issue_inp1(3, 6);
        }
        else if (s == 4) {
            asm volatile("s_waitcnt vmcnt(2)" ::: "memory");   // batch B in
            __builtin_amdgcn_sched_barrier(0);
            write_inp1(3, 6); issue_inp1(6, 9);
        }
        else if (s == 6) {
            asm volatile("s_waitcnt vmcnt(2)" ::: "memory");   // batch C in
            __builtin_amdgcn_sched_barrier(0);
            write_inp1(6, 9); issue_inp1(9, 11);
        }
        else if (s == 8) {
            asm volatile("s_waitcnt vmcnt(2)" ::: "memory");   // batch D in
            __builtin_amdgcn_sched_barrier(0);
            write_inp1(9, 11);
        }

        const int buf = s % 3;
        const int hh = (s < 9) ? 0 : 1;
        const int p  = (s < 9) ? s : s - 9;
        const int kh = p / 3, kw = p - kh * 3;

        // kern fragments: co = nf*16+l15, ci-chunk hi4 within this half
        bf16x8 Kf[4];
#pragma unroll
        for (int nf = 0; nf < 4; ++nf) {
            const int co = nf * 16 + l15;
            Kf[nf] = *(const bf16x8*)((const char*)kn_lds +
                      ((buf << 12) + (co << 6) +
                       ((hi4 << 4) ^ (((co >> 1) & 3) << 4))));
        }

        const int q = l15 + kw;
        const int swz = (q & 7) << 4;
        const int c2 = (hh << 6) | (hi4 << 4);
#pragma unroll
        for (int mf = 0; mf < 4; ++mf) {
            const int r = wv * 4 + mf + kh;
            bf16x8 Af = *(const bf16x8*)((const char*)in_lds +
                          (((r * 18 + q) << 7) + (c2 ^ swz)));
#pragma unroll
            for (int nf = 0; nf < 4; ++nf)
                acc[mf][nf] = __builtin_amdgcn_mfma_f32_16x16x32_bf16(
                    Kf[nf], Af, acc[mf][nf], 0, 0, 0);
        }
    }

    __syncthreads();     // all waves done reading in_lds before overwrite

    // ---- LDS-transpose epilogue (wave-private 4 KB region). Plain cached
    // stores, 1 KB contiguous per wave-instruction (R6-verified:
    // WRITE_SIZE exactly ideal).
    char* ep = (char*)in_lds + (wv << 12);
#pragma unroll
    for (int mf = 0; mf < 4; ++mf) {
        const int iloc = wv * 4 + mf;
        const size_t rowoff = ((size_t)b << 16) +
                              (size_t)(gi * 128 + i0 + iloc) * 256 + (size_t)(gj * 128 + j0);
        // scatter: lane(l15,hi4) holds co = nf*16+hi4*4+reg at pixel l15
#pragma unroll
        for (int nf = 0; nf < 4; ++nf) {
            const int off = (nf * 64 + hi4 * 16) ^ ((l15 & 7) << 4);
            *(f32x4*)(ep + l15 * 256 + off) = acc[mf][nf];
        }
        // gather: lane(l15,hi4) reads co-chunk l15 of pixel t*4+hi4
#pragma unroll
        for (int t = 0; t < 4; ++t) {
            const int px = t * 4 + hi4;
            f32x4 vv4 = *(const f32x4*)(ep + px * 256 + ((l15 << 4) ^ ((px & 7) << 4)));
            *(f32x4*)(out + (rowoff + px) * 64 + l15 * 4) = vv4;
        }
    }
}

// ---------------------------------------------------------------------------
extern "C" void kernel_launch(void* const* d_in, const int* in_sizes, int n_in,
                              void* d_out, int out_size, void* d_ws, size_t ws_size,
                              hipStream_t stream)
{
    const float* x      = (const float*)d_in[0];
    const float* conv_w = (const float*)d_in[1];
    const float* qkv_w  = (const float*)d_in[2];
    const float* qkv_b  = (const float*)d_in[3];
    const float* proj_w = (const float*)d_in[4];
    const float* proj_b = (const float*)d_in[5];
    const float* se_w1  = (const float*)d_in[6];
    const float* se_b1  = (const float*)d_in[7];
    const float* se_w2  = (const float*)d_in[8];
    const float* se_b2  = (const float*)d_in[9];
    float* out = (float*)d_out;

    float* qv = (float*)d_ws;            // 147456 f
    float* kv = qv + 147456;             // 147456 f
    float* vv = kv + 147456;             // 147456 f
    float* ao = vv + 147456;             // 147456 f
    ushort* kb = (ushort*)(ao + 147456); // 147456 u16  (total ~2.6 MB)

    hipLaunchKernelGGL(qkv_kernel, dim3(2304), dim3(192), 0, stream,
                       conv_w, qkv_w, qkv_b, qv, kv, vv);
    hipLaunchKernelGGL(attn_kernel, dim3(512), dim3(64), 0, stream, qv, kv, vv, ao);
    hipLaunchKernelGGL(proj_se_kernel, dim3(256), dim3(64), 0, stream,
                       ao, proj_w, proj_b, se_w1, se_b1, se_w2, se_b2, kb);
    hipLaunchKernelGGL(conv_kernel, dim3(2048), dim3(256), 0, stream, x, kb, out);
}

// Round 13
// 84.221 us; speedup vs baseline: 1.5519x; 1.3525x over previous
//
#include <hip/hip_runtime.h>
#include <hip/hip_bf16.h>

typedef __bf16 bf16x8 __attribute__((ext_vector_type(8)));
typedef float  f32x4  __attribute__((ext_vector_type(4)));

// ---------------------------------------------------------------------------
// Stage 1: qkv = kern_tok @ qkv_w + qkv_b ; split into q(scaled),k,v
// ---------------------------------------------------------------------------
__global__ __launch_bounds__(192) void qkv_kernel(
    const float* __restrict__ conv_w, const float* __restrict__ qkv_w,
    const float* __restrict__ qkv_b,
    float* __restrict__ qv, float* __restrict__ kvv, float* __restrict__ vv)
{
    __shared__ float tok[64];
    const int bid = blockIdx.x;          // co*36 + s
    const int co = bid / 36, s = bid - co * 36;
    const int w = s / 9, p = s - w * 9;
    const int t = threadIdx.x;           // 192
    if (t < 64) tok[t] = conv_w[(((w * 64 + co) * 64 + t) * 9) + p];
    __syncthreads();
    float acc = qkv_b[t];
#pragma unroll 8
    for (int ci = 0; ci < 64; ++ci) acc += tok[ci] * qkv_w[ci * 192 + t];
    const int trip = t >> 6, rem = t & 63, h = rem >> 3, d = rem & 7;
    if (trip == 0) acc *= 0.35355339059327373f;   // hd^-0.5, hd=8
    float* dst = (trip == 0) ? qv : ((trip == 1) ? kvv : vv);
    dst[((co * 8 + h) * 36 + s) * 8 + d] = acc;
}

// ---------------------------------------------------------------------------
// Stage 2: attention per (co, head): softmax(q k^T) v  -> ao[co][s][h*8+d]
// ---------------------------------------------------------------------------
__global__ __launch_bounds__(64) void attn_kernel(
    const float* __restrict__ qv, const float* __restrict__ kvv,
    const float* __restrict__ vv, float* __restrict__ ao)
{
    __shared__ float kl[288], vl[288];
    const int bid = blockIdx.x;          // co*8 + h
    const int t = threadIdx.x;           // 64
    const float* kb = kvv + bid * 288;
    const float* vb = vv + bid * 288;
    for (int i = t; i < 288; i += 64) { kl[i] = kb[i]; vl[i] = vb[i]; }
    __syncthreads();
    if (t < 36) {
        float q[8];
        const float* qb = qv + bid * 288 + t * 8;
#pragma unroll
        for (int d = 0; d < 8; ++d) q[d] = qb[d];
        float sc[36];
        float mx = -1e30f;
#pragma unroll
        for (int u = 0; u < 36; ++u) {
            float a = 0.f;
#pragma unroll
            for (int d = 0; d < 8; ++d) a += q[d] * kl[u * 8 + d];
            sc[u] = a;
            mx = fmaxf(mx, a);
        }
        float sum = 0.f;
        float o[8] = {0.f,0.f,0.f,0.f,0.f,0.f,0.f,0.f};
#pragma unroll
        for (int u = 0; u < 36; ++u) {
            float e = expf(sc[u] - mx);
            sum += e;
#pragma unroll
            for (int d = 0; d < 8; ++d) o[d] += e * vl[u * 8 + d];
        }
        const float inv = 1.0f / sum;
        const int co = bid >> 3, h = bid & 7;
        float* dst = ao + (co * 36 + t) * 64 + h * 8;
#pragma unroll
        for (int d = 0; d < 8; ++d) dst[d] = o[d] * inv;
    }
}

// ---------------------------------------------------------------------------
// Stage 3: proj + SE + write bf16 kernels.
// kout layout: [((h*4 + w)*9 + p)][co][ci32]  (4 KB chunks = one
// (tap, ci-half); conv stages exactly one chunk per pipeline stage).
// ---------------------------------------------------------------------------
__global__ __launch_bounds__(64) void proj_se_kernel(
    const float* __restrict__ ao, const float* __restrict__ proj_w,
    const float* __restrict__ proj_b,
    const float* __restrict__ se_w1, const float* __restrict__ se_b1,
    const float* __restrict__ se_w2, const float* __restrict__ se_b2,
    ushort* __restrict__ kout)
{
    __shared__ float al[9][64];
    __shared__ float pool[64];
    __shared__ float hb[4];
    const int bid = blockIdx.x;          // w*64 + co
    const int w = bid >> 6, co = bid & 63;
    const int t = threadIdx.x;           // 64 (= ci)
    for (int i = t; i < 576; i += 64) {
        int p = i >> 6, j = i & 63;
        al[p][j] = ao[(co * 36 + w * 9 + p) * 64 + j];
    }
    __syncthreads();
    float kv[9];
#pragma unroll
    for (int p = 0; p < 9; ++p) {
        float a = proj_b[t];
#pragma unroll 8
        for (int j = 0; j < 64; ++j) a += al[p][j] * proj_w[j * 64 + t];
        kv[p] = a;
    }
    float pl = 0.f;
#pragma unroll
    for (int p = 0; p < 9; ++p) pl += kv[p];
    pool[t] = pl * (1.0f / 9.0f);
    __syncthreads();
    if (t < 4) {
        float hh = se_b1[w * 4 + t];
#pragma unroll 8
        for (int c = 0; c < 64; ++c) hh += pool[c] * se_w1[(w * 4 + t) * 64 + c];
        hb[t] = fmaxf(hh, 0.0f);
    }
    __syncthreads();
    float z = se_b2[w * 64 + t];
#pragma unroll
    for (int d = 0; d < 4; ++d) z += hb[d] * se_w2[(w * 64 + t) * 4 + d];
    const float sg = 1.0f / (1.0f + expf(-z));
    const int hhalf = t >> 5, ci32 = t & 31;
#pragma unroll
    for (int p = 0; p < 9; ++p) {
        __hip_bfloat16 hv = __float2bfloat16(kv[p] * sg);
        kout[(((hhalf * 4 + w) * 9) + p) * 2048 + co * 32 + ci32] = *(const ushort*)&hv;
    }
}

// ---------------------------------------------------------------------------
// Stage 4: dynamic per-window 3x3 conv, implicit GEMM, bf16 MFMA.
//
// Round-13 = R6 (verified best, 84.2 us e2e) restored, with two surgical
// scheduling deltas (R7-R12 all regressed: compiler load-sinking, (256,4)
// spill wall, weave conflicts -- all reverted):
//  1. stage_kern(s+2) issued immediately AFTER the barrier, BEFORE the
//     16 MFMAs (R6 issued after). Buffer safety identical (all waves past
//     barrier => done reading buf (s-1)%3 = (s+2)%3); vmcnt accounting
//     identical (entering stage s, outstanding = {s, s+1} either way).
//     The load gains one full compute phase (~300 cyc) of latency window.
//  2. Tail fix: s=17's queue is {17} alone, so R6's unconditional vmcnt(1)
//     could pass before set 17 landed. s=17 now uses vmcnt(0).
// Structure (R6-verified): kern TRIPLE buffer 3x4 KB via global_load_lds
// (linear dest + pre-swizzled global source), counted vmcnt(1) never 0
// mid-loop, raw s_barrier per stage, full-channel in_lds 41472 B with the
// 0-conflict col-XOR swizzle, deep 21-load prologue staging, LDS-transpose
// epilogue with plain cached 1 KB-contiguous stores (WRITE exactly ideal).
// LDS 53760 B -> 3 blocks/CU at (256,3).
// ---------------------------------------------------------------------------
__global__ __launch_bounds__(256, 3) void conv_kernel(
    const float* __restrict__ x, const ushort* __restrict__ kern,
    float* __restrict__ out)
{
    __shared__ alignas(16) ushort in_lds[18 * 18 * 64];   // 41472 B
    __shared__ alignas(16) ushort kn_lds[3 * 2048];       // 12288 B (3 x 4KB)

    const int tid = threadIdx.x;

    // ---- XCD-chunked bijective remap: XCD k processes nb in [k*256,(k+1)*256)
    const int bid = blockIdx.x;                 // 0..2047, xcd = bid & 7
    const int nb  = ((bid & 7) << 8) + (bid >> 3);
    const int bz  = nb >> 6;                    // (w*8+b), 4 per XCD
    const int rem = nb & 63;
    const int i0  = (rem >> 3) << 4;
    const int j0  = (rem & 7) << 4;
    const int w = bz >> 3, b = bz & 7;
    const int gi = w >> 1, gj = w & 1;

    const int wv   = tid >> 6;
    const int lane = tid & 63;
    const int l15  = lane & 15;
    const int hi4  = lane >> 4;        // 0..3

    // ---- async kern stage: stage s = (p = s>>1, half = s&1) -> one 4 KB
    // chunk at kern + (((half*4+w)*9)+p)*4096. Linear LDS dest; read-side
    // swizzle realized by pre-swizzling the GLOBAL source (both-sides rule).
    const char* kern_b = (const char*)kern;
    const int ksrc = (lane << 4) ^ (((lane >> 3) & 3) << 4);
    auto stage_kern = [&](int s, int buf) {
        const int p = s >> 1, hh = s & 1;
        const char* gs = kern_b + ((size_t)((((hh * 4 + w) * 9)) + p) << 12);
        __builtin_amdgcn_global_load_lds(
            (const __attribute__((address_space(1))) unsigned int*)(gs + (wv << 10) + ksrc),
            (__attribute__((address_space(3))) unsigned int*)
                ((char*)kn_lds + (buf << 12) + (wv << 10)),
            16, 0, 0);
    };

    // ---- prologue: issue kern stages 0,1 first (they fly under the input
    // staging burst), then stage the FULL input tile, then ONE full drain.
    stage_kern(0, 0);
    stage_kern(1, 1);

    // input staging, FULL 64 channels: 18x18 px * 128 B, 16 thr/px (4 ch).
    // All 21 clamped loads issued before the cvt/write pass (deep flight).
    // LDS position: (pp<<7) + ((cc*2) ^ ((q&7)<<4))  [0-conflict swizzle]
    {
        const int cc = (tid & 15) << 2;    // channel 0..60
        const int p0 = tid >> 4;           // 0..15
        float4 v[21];
        unsigned okm = 0;
#pragma unroll
        for (int k = 0; k < 21; ++k) {
            const int pp = p0 + (k << 4);          // <= 335
            const int ppc = pp < 323 ? pp : 323;
            const int r = ppc / 18, q = ppc - r * 18;
            const int iy = i0 - 1 + r, jx = j0 - 1 + q;
            const bool ok = (pp < 324) & (iy >= 0) & (iy < 128) & (jx >= 0) & (jx < 128);
            const int iyc = iy < 0 ? 0 : (iy > 127 ? 127 : iy);
            const int jxc = jx < 0 ? 0 : (jx > 127 ? 127 : jx);
            const size_t xi = (((size_t)b << 16) +
                               (size_t)(gi * 128 + iyc) * 256 + (size_t)(gj * 128 + jxc)) * 64 + cc;
            v[k] = *(const float4*)(x + xi);
            okm |= (unsigned)ok << k;
        }
#pragma unroll
        for (int k = 0; k < 21; ++k) {
            const int pp = p0 + (k << 4);
            if (pp < 324) {
                const int r = pp / 18, q = pp - r * 18;
                float4 z = (okm >> k) & 1 ? v[k] : make_float4(0.f, 0.f, 0.f, 0.f);
                union { ushort4 u; ushort h4[4]; } tmp;
                __hip_bfloat16 b0 = __float2bfloat16(z.x); tmp.h4[0] = *(const ushort*)&b0;
                __hip_bfloat16 b1 = __float2bfloat16(z.y); tmp.h4[1] = *(const ushort*)&b1;
                __hip_bfloat16 b2 = __float2bfloat16(z.z); tmp.h4[2] = *(const ushort*)&b2;
                __hip_bfloat16 b3 = __float2bfloat16(z.w); tmp.h4[3] = *(const ushort*)&b3;
                *(ushort4*)((char*)in_lds +
                    ((pp << 7) + ((cc << 1) ^ ((q & 7) << 4)))) = tmp.u;
            }
        }
    }

    f32x4 acc[4][4];
#pragma unroll
    for (int mf = 0; mf < 4; ++mf)
#pragma unroll
        for (int nf = 0; nf < 4; ++nf)
            acc[mf][nf] = (f32x4){0.f, 0.f, 0.f, 0.f};

    __syncthreads();     // the ONE full drain: input ds_writes + kern 0,1

#pragma unroll
    for (int s = 0; s < 18; ++s) {
        // counted wait: set s retired when <=1 outstanding ({s, s+1} in
        // flight at stage top; s+2 issued after this stage's barrier).
        // s=17: queue is {17} alone -> must be vmcnt(0) (R6 latent race fix).
        if (s < 17) asm volatile("s_waitcnt vmcnt(1)" ::: "memory");
        else        asm volatile("s_waitcnt vmcnt(0)" ::: "memory");
        __builtin_amdgcn_sched_barrier(0);
        __builtin_amdgcn_s_barrier();      // all waves' set-s loads in LDS
        __builtin_amdgcn_sched_barrier(0);

        // issue load(s+2) into buf[(s+2)%3] NOW (before compute): all waves
        // passed this stage's barrier => all finished compute(s-1) = last
        // readers of that buffer. Gains ~1 compute phase of latency window.
        if (s < 16) stage_kern(s + 2, (s + 2) % 3);

        const int buf = s % 3;
        const int p = s >> 1, hh = s & 1;
        const int kh = p / 3, kw = p - kh * 3;

        // kern fragments: co = nf*16+l15, ci-chunk hi4 within this half
        bf16x8 Kf[4];
#pragma unroll
        for (int nf = 0; nf < 4; ++nf) {
            const int co = nf * 16 + l15;
            Kf[nf] = *(const bf16x8*)((const char*)kn_lds +
                      ((buf << 12) + (co << 6) +
                       ((hi4 << 4) ^ (((co >> 1) & 3) << 4))));
        }

        const int q = l15 + kw;
        const int swz = (q & 7) << 4;
        const int c2 = (hh << 6) | (hi4 << 4);
#pragma unroll
        for (int mf = 0; mf < 4; ++mf) {
            const int r = wv * 4 + mf + kh;
            bf16x8 Af = *(const bf16x8*)((const char*)in_lds +
                          (((r * 18 + q) << 7) + (c2 ^ swz)));
#pragma unroll
            for (int nf = 0; nf < 4; ++nf)
                acc[mf][nf] = __builtin_amdgcn_mfma_f32_16x16x32_bf16(
                    Kf[nf], Af, acc[mf][nf], 0, 0, 0);
        }
    }

    // ---- pre-epilogue barrier: my ds_reads retired (lgkm 0), then all
    // waves arrive => nobody still reads in_lds when we overwrite it.
    asm volatile("s_waitcnt lgkmcnt(0)" ::: "memory");
    __builtin_amdgcn_sched_barrier(0);
    __builtin_amdgcn_s_barrier();
    __builtin_amdgcn_sched_barrier(0);

    // ---- LDS-transpose epilogue (wave-private 4 KB region). Plain cached
    // stores, 1 KB contiguous per wave-instruction.
    char* ep = (char*)in_lds + (wv << 12);
#pragma unroll
    for (int mf = 0; mf < 4; ++mf) {
        const int iloc = wv * 4 + mf;
        const size_t rowoff = ((size_t)b << 16) +
                              (size_t)(gi * 128 + i0 + iloc) * 256 + (size_t)(gj * 128 + j0);
        // scatter: lane(l15,hi4) holds co = nf*16+hi4*4+reg at pixel l15
#pragma unroll
        for (int nf = 0; nf < 4; ++nf) {
            const int off = (nf * 64 + hi4 * 16) ^ ((l15 & 7) << 4);
            *(f32x4*)(ep + l15 * 256 + off) = acc[mf][nf];
        }
        // gather: lane(l15,hi4) reads co-chunk l15 of pixel t*4+hi4
#pragma unroll
        for (int t = 0; t < 4; ++t) {
            const int px = t * 4 + hi4;
            f32x4 vv4 = *(const f32x4*)(ep + px * 256 + ((l15 << 4) ^ ((px & 7) << 4)));
            *(f32x4*)(out + (rowoff + px) * 64 + l15 * 4) = vv4;
        }
    }
}

// ---------------------------------------------------------------------------
extern "C" void kernel_launch(void* const* d_in, const int* in_sizes, int n_in,
                              void* d_out, int out_size, void* d_ws, size_t ws_size,
                              hipStream_t stream)
{
    const float* x      = (const float*)d_in[0];
    const float* conv_w = (const float*)d_in[1];
    const float* qkv_w  = (const float*)d_in[2];
    const float* qkv_b  = (const float*)d_in[3];
    const float* proj_w = (const float*)d_in[4];
    const float* proj_b = (const float*)d_in[5];
    const float* se_w1  = (const float*)d_in[6];
    const float* se_b1  = (const float*)d_in[7];
    const float* se_w2  = (const float*)d_in[8];
    const float* se_b2  = (const float*)d_in[9];
    float* out = (float*)d_out;

    float* qv = (float*)d_ws;            // 147456 f
    float* kv = qv + 147456;             // 147456 f
    float* vv = kv + 147456;             // 147456 f
    float* ao = vv + 147456;             // 147456 f
    ushort* kb = (ushort*)(ao + 147456); // 147456 u16  (total ~2.6 MB)

    hipLaunchKernelGGL(qkv_kernel, dim3(2304), dim3(192), 0, stream,
                       conv_w, qkv_w, qkv_b, qv, kv, vv);
    hipLaunchKernelGGL(attn_kernel, dim3(512), dim3(64), 0, stream, qv, kv, vv, ao);
    hipLaunchKernelGGL(proj_se_kernel, dim3(256), dim3(64), 0, stream,
                       ao, proj_w, proj_b, se_w1, se_b1, se_w2, se_b2, kb);
    hipLaunchKernelGGL(conv_kernel, dim3(2048), dim3(256), 0, stream, x, kb, out);
}